// Round 17
// baseline (509.458 us; speedup 1.0000x reference)
//
#include <hip/hip_runtime.h>
#include <cstdint>
#include <cstddef>

#define N_NODES 50000
#define N_EDGES 1600000
#define D 512
#define MPAD 50048   // 391 * 128, padded M for GEMM tiles
#define NPX 6250     // nodes per XCD dest-range (50000/8)
#define CAP 80       // bucket capacity; Poisson(32) tail beyond 80 ~ 4e-12/row
#define TILE_SHIFT 11          // 2048-row source tiles (1 MB of xq each)
#define NTILES 25              // ceil(50000/2048)

typedef __attribute__((ext_vector_type(8))) short bf16x8;
typedef __attribute__((ext_vector_type(4))) float f32x4;
typedef __attribute__((ext_vector_type(8))) unsigned short u16x8;
typedef __attribute__((ext_vector_type(4))) int i32x4;

static __device__ __forceinline__ unsigned short f2bf(float f) {
  unsigned u = __float_as_uint(f);
  u += 0x7fffu + ((u >> 16) & 1u);   // RNE
  return (unsigned short)(u >> 16);
}

// ---------------- prep: x -> biased-u8 + scale; W -> per-col-s8 wbT + wscale; zero cnt ----------------
// [0,12500): 1 wave = 1 row of x. rowmax shfl_xor; u = rint(x*127/max)+128.
// [12500,12628): 64x64 tile of w0/w1 -> colmax scan (full Wcat column, redundant per
//   tile) -> transpose-quantize s8 into wbT[j][k] = rint(Wcat[k][j]*127/colmax_j).
//   Tiles with m==0,k0==0 write wscale[j]=colmax_j/127.
// [12628,12726): zero cnt[100000].
__global__ __launch_bounds__(256) void prep(const float* __restrict__ x,
                                            const float* __restrict__ w0,
                                            const float* __restrict__ w1,
                                            unsigned char* __restrict__ xq,
                                            float* __restrict__ scale,
                                            signed char* __restrict__ wbT,
                                            float* __restrict__ wscale,
                                            int* __restrict__ cnt) {
  __shared__ float ts[64][68];
  __shared__ float cmax[4][64];
  __shared__ float cinv[64];
  const int t = threadIdx.x;
  if (blockIdx.x < 12500) {
    const int lane = t & 63;
    const int wave = t >> 6;
    const int n = blockIdx.x * 4 + wave;
    const float* xr = x + (size_t)n * D + lane * 8;
    f32x4 f0 = __builtin_nontemporal_load((const f32x4*)xr);
    f32x4 f1 = __builtin_nontemporal_load((const f32x4*)xr + 1);
    float m = fmaxf(fmaxf(fmaxf(fabsf(f0[0]), fabsf(f0[1])), fmaxf(fabsf(f0[2]), fabsf(f0[3]))),
                    fmaxf(fmaxf(fabsf(f1[0]), fabsf(f1[1])), fmaxf(fabsf(f1[2]), fabsf(f1[3]))));
    #pragma unroll
    for (int off = 32; off >= 1; off >>= 1) m = fmaxf(m, __shfl_xor(m, off, 64));
    m = fmaxf(m, 1e-20f);
    const float inv = 127.0f / m;
    int q[8];
    q[0] = (int)rintf(f0[0] * inv) + 128; q[1] = (int)rintf(f0[1] * inv) + 128;
    q[2] = (int)rintf(f0[2] * inv) + 128; q[3] = (int)rintf(f0[3] * inv) + 128;
    q[4] = (int)rintf(f1[0] * inv) + 128; q[5] = (int)rintf(f1[1] * inv) + 128;
    q[6] = (int)rintf(f1[2] * inv) + 128; q[7] = (int)rintf(f1[3] * inv) + 128;
    unsigned lo = (q[0] & 0xff) | ((q[1] & 0xff) << 8) | ((q[2] & 0xff) << 16) | ((unsigned)(q[3] & 0xff) << 24);
    unsigned hi = (q[4] & 0xff) | ((q[5] & 0xff) << 8) | ((q[6] & 0xff) << 16) | ((unsigned)(q[7] & 0xff) << 24);
    *(uint2*)(xq + (size_t)n * D + lane * 8) = make_uint2(lo, hi);
    if (lane == 0) scale[n] = m * (1.0f / 127.0f);
  } else if (blockIdx.x < 12628) {
    const int bid2 = blockIdx.x - 12500;    // 0..127
    const int m = bid2 >> 6;                // 0: w0, 1: w1
    const int tile = bid2 & 63;
    const int k0 = (tile >> 3) * 64;
    const int j0 = (tile & 7) * 64;
    const float* W = m ? w1 : w0;
    // column-max over the full 1024-row Wcat column (coalesced: lane = col)
    const int lane = t & 63;
    const int wv = t >> 6;
    float mx = 0.f;
    #pragma unroll 8
    for (int k = wv * 256; k < wv * 256 + 256; ++k) {
      const float* Wk = (k < 512) ? (w0 + (size_t)k * 512) : (w1 + (size_t)(k - 512) * 512);
      mx = fmaxf(mx, fabsf(Wk[j0 + lane]));
    }
    cmax[wv][lane] = mx;
    __syncthreads();
    if (t < 64) {
      float c = fmaxf(fmaxf(cmax[0][t], cmax[1][t]), fmaxf(cmax[2][t], cmax[3][t]));
      c = fmaxf(c, 1e-20f);
      cinv[t] = 127.0f / c;
      if (m == 0 && k0 == 0) wscale[j0 + t] = c * (1.0f / 127.0f);
    }
    __syncthreads();
    // load 64x64 tile, transpose-quantize to s8
    const int tr = t >> 4;
    const int tc = (t & 15) * 4;
    #pragma unroll
    for (int it = 0; it < 4; ++it) {
      int kk = tr + it * 16;
      float4 v = *(const float4*)&W[(size_t)(k0 + kk) * 512 + j0 + tc];
      ts[kk][tc] = v.x; ts[kk][tc + 1] = v.y; ts[kk][tc + 2] = v.z; ts[kk][tc + 3] = v.w;
    }
    __syncthreads();
    const int jl = t >> 3;
    const int kl = (t & 7) * 8;
    #pragma unroll
    for (int it = 0; it < 2; ++it) {
      int j = jl + it * 32;
      float inv = cinv[j];
      unsigned lo = 0, hi = 0;
      #pragma unroll
      for (int q2 = 0; q2 < 4; ++q2) {
        int q = (int)rintf(ts[kl + q2][j] * inv);
        lo |= ((unsigned)(q & 0xff)) << (8 * q2);
      }
      #pragma unroll
      for (int q2 = 4; q2 < 8; ++q2) {
        int q = (int)rintf(ts[kl + q2][j] * inv);
        hi |= ((unsigned)(q & 0xff)) << (8 * (q2 - 4));
      }
      *(uint2*)&wbT[(size_t)(j0 + j) * 1024 + m * 512 + k0 + kl] = make_uint2(lo, hi);
    }
  } else {
    int q2 = (int)(blockIdx.x - 12628) * 256 + t;
    if (q2 < 25000) ((i32x4*)cnt)[q2] = (i32x4)0;
  }
}

// ---------------- bucket fill, XCD-local dest ranges ----------------
// Edge packed 4B: col(u16) | bf16(v * scale[col]) << 16 — scale folded here.
__global__ __launch_bounds__(256) void fill_bucket(
    const int* __restrict__ r0, const int* __restrict__ co0, const float* __restrict__ v0,
    const int* __restrict__ r1, const int* __restrict__ co1, const float* __restrict__ v1,
    const float* __restrict__ scale,
    int* __restrict__ cnt0, int* __restrict__ cnt1,
    unsigned* __restrict__ e0, unsigned* __restrict__ e1) {
  const int nq = N_EDGES / 4;
  const int lo = (int)(blockIdx.x & 7) * NPX;
  const int hi = lo + NPX;
  const int stride = (1024 >> 3) * 256;
  for (int i = (int)(blockIdx.x >> 3) * 256 + threadIdx.x; i < 2 * nq; i += stride) {
    if (i < nq) {
      i32x4 r = ((const i32x4*)r0)[i];
      i32x4 c = ((const i32x4*)co0)[i];
      f32x4 v = ((const f32x4*)v0)[i];
      #pragma unroll
      for (int k = 0; k < 4; ++k) {
        if (r[k] >= lo && r[k] < hi) {
          int slot = atomicAdd(&cnt0[r[k]], 1);
          if (slot < CAP)
            e0[(size_t)r[k] * CAP + slot] =
                (unsigned)c[k] | ((unsigned)f2bf(v[k] * scale[c[k]]) << 16);
        }
      }
    } else {
      int j = i - nq;
      i32x4 r = ((const i32x4*)r1)[j];
      i32x4 c = ((const i32x4*)co1)[j];
      f32x4 v = ((const f32x4*)v1)[j];
      #pragma unroll
      for (int k = 0; k < 4; ++k) {
        if (r[k] >= lo && r[k] < hi) {
          int slot = atomicAdd(&cnt1[r[k]], 1);
          if (slot < CAP)
            e1[(size_t)r[k] * CAP + slot] =
                (unsigned)c[k] | ((unsigned)f2bf(v[k] * scale[c[k]]) << 16);
        }
      }
    }
  }
}

// a[i] += v * u8_i  (biased); compiler lowers byte-extract+cvt to v_cvt_f32_ubyte0..3
static __device__ __forceinline__ void acc8u(float* a, uint2 q, float v) {
  a[0] += v * (float)(q.x & 0xffu);
  a[1] += v * (float)((q.x >> 8) & 0xffu);
  a[2] += v * (float)((q.x >> 16) & 0xffu);
  a[3] += v * (float)((q.x >> 24) & 0xffu);
  a[4] += v * (float)(q.y & 0xffu);
  a[5] += v * (float)((q.y >> 8) & 0xffu);
  a[6] += v * (float)((q.y >> 16) & 0xffu);
  a[7] += v * (float)((q.y >> 24) & 0xffu);
}

// ---------------- SpMM (biased-u8 gather), s output quantized to s8 + per-row scale ----------------
// Gather loop byte-identical to the proven round-15/16 kernel. Epilogue: debias,
// wave row-max (shfl_xor), quantize s-row to s8, store 8B/lane/half + sscale[n].
__global__ __launch_bounds__(256) void spmm_sorted(const unsigned char* __restrict__ xq,
    const int* __restrict__ cnt0, const unsigned* __restrict__ e0,
    const int* __restrict__ cnt1, const unsigned* __restrict__ e1,
    signed char* __restrict__ sq, float* __restrict__ sscale) {
  __shared__ unsigned sed[4][2][CAP];
  __shared__ int cur[4][2][NTILES];
  __shared__ unsigned short starts[4][2][NTILES + 1];
  const int t = threadIdx.x;
  const int lane = t & 63;
  const int wave = t >> 6;
  const int n = blockIdx.x * 4 + wave;   // 12500 blocks * 4 waves = 50000 rows
  const int c0 = lane * 8;               // 8 bytes per lane

  int deg0 = cnt0[n]; if (deg0 > CAP) deg0 = CAP;
  int deg1 = cnt1[n]; if (deg1 > CAP) deg1 = CAP;
  const unsigned* eb0 = e0 + (size_t)n * CAP;
  const unsigned* eb1 = e1 + (size_t)n * CAP;

  // zero histograms
  for (int b = lane; b < 2 * NTILES; b += 64) ((int*)cur[wave])[b] = 0;
  __syncthreads();

  // load edges (coalesced, stash in regs) + histogram by src-tile
  unsigned my0[2] = {0u, 0u}, my1[2] = {0u, 0u};
  #pragma unroll
  for (int q = 0; q < 2; ++q) {
    int p = lane + q * 64;
    if (p < deg0) {
      unsigned m = eb0[p]; my0[q] = m;
      atomicAdd(&cur[wave][0][(m & 0xffffu) >> TILE_SHIFT], 1);
    }
    if (p < deg1) {
      unsigned m = eb1[p]; my1[q] = m;
      atomicAdd(&cur[wave][1][(m & 0xffffu) >> TILE_SHIFT], 1);
    }
  }
  __syncthreads();

  // exclusive prefix (lane 0 -> sup0, lane 1 -> sup1); cur becomes the cursor
  if (lane < 2) {
    int acc2 = 0;
    for (int t2 = 0; t2 < NTILES; ++t2) {
      starts[wave][lane][t2] = (unsigned short)acc2;
      int h = cur[wave][lane][t2];
      cur[wave][lane][t2] = acc2;
      acc2 += h;
    }
    starts[wave][lane][NTILES] = (unsigned short)acc2;
  }
  __syncthreads();

  // scatter into sorted order
  #pragma unroll
  for (int q = 0; q < 2; ++q) {
    int p = lane + q * 64;
    if (p < deg0) {
      unsigned m = my0[q];
      int pos = atomicAdd(&cur[wave][0][(m & 0xffffu) >> TILE_SHIFT], 1);
      sed[wave][0][pos] = m;
    }
    if (p < deg1) {
      unsigned m = my1[q];
      int pos = atomicAdd(&cur[wave][1][(m & 0xffffu) >> TILE_SHIFT], 1);
      sed[wave][1][pos] = m;
    }
  }
  __syncthreads();

  // Phase B: tile-ordered gather-accumulate (ubyte dequant), track sum(v) per support
  float acc[2][8] = {};
  float sumv[2] = {0.f, 0.f};
  for (int t2 = 0; t2 < NTILES; ++t2) {
    #pragma unroll
    for (int sup = 0; sup < 2; ++sup) {
      float* a = acc[sup];
      float sv = 0.f;
      int p = starts[wave][sup][t2];
      const int pe = starts[wave][sup][t2 + 1];
      for (; p + 1 < pe; p += 2) {
        unsigned mA = sed[wave][sup][p];      // wave-uniform: LDS broadcast
        unsigned mB = sed[wave][sup][p + 1];
        uint2 qA = *(const uint2*)(xq + (size_t)(mA & 0xffffu) * D + c0);
        uint2 qB = *(const uint2*)(xq + (size_t)(mB & 0xffffu) * D + c0);
        float vA = __uint_as_float(mA & 0xffff0000u);
        float vB = __uint_as_float(mB & 0xffff0000u);
        acc8u(a, qA, vA);
        acc8u(a, qB, vB);
        sv += vA + vB;
      }
      if (p < pe) {
        unsigned m = sed[wave][sup][p];
        uint2 q = *(const uint2*)(xq + (size_t)(m & 0xffffu) * D + c0);
        float v = __uint_as_float(m & 0xffff0000u);
        acc8u(a, q, v);
        sv += v;
      }
      sumv[sup] += sv;
    }
  }

  // Epilogue: debias, row-max over both halves, quantize to s8
  float f0[8], f1[8];
  #pragma unroll
  for (int i = 0; i < 8; ++i) {
    f0[i] = acc[0][i] - 128.0f * sumv[0];
    f1[i] = acc[1][i] - 128.0f * sumv[1];
  }
  float m = 0.f;
  #pragma unroll
  for (int i = 0; i < 8; ++i) m = fmaxf(m, fmaxf(fabsf(f0[i]), fabsf(f1[i])));
  #pragma unroll
  for (int off = 32; off >= 1; off >>= 1) m = fmaxf(m, __shfl_xor(m, off, 64));
  m = fmaxf(m, 1e-20f);
  const float inv = 127.0f / m;
  unsigned lo0 = 0, hi0 = 0, lo1 = 0, hi1 = 0;
  #pragma unroll
  for (int i = 0; i < 4; ++i) {
    int q0 = (int)rintf(f0[i] * inv);     lo0 |= ((unsigned)(q0 & 0xff)) << (8 * i);
    int q4 = (int)rintf(f0[i + 4] * inv); hi0 |= ((unsigned)(q4 & 0xff)) << (8 * i);
    int r0 = (int)rintf(f1[i] * inv);     lo1 |= ((unsigned)(r0 & 0xff)) << (8 * i);
    int r4 = (int)rintf(f1[i + 4] * inv); hi1 |= ((unsigned)(r4 & 0xff)) << (8 * i);
  }
  *(uint2*)(sq + (size_t)n * 1024 + c0) = make_uint2(lo0, hi0);
  *(uint2*)(sq + (size_t)n * 1024 + 512 + c0) = make_uint2(lo1, hi1);
  if (lane == 0) sscale[n] = m * (1.0f / 127.0f);
}

// ---------------- GEMM (i8): out = relu( sscale_n * (sq @ wbT^T)_i32 * wscale_j + b ) ----------------
// BM=128, BN=256, BK=64 i8 (= 64 B/row, identical byte geometry & swizzle to the
// proven bf16 BK=32 kernel). mfma_i32_16x16x64_i8: 16 K-steps, 32 MFMA each.
#define BM 128
#define BN 256
#define BKB 64   // bytes per row per K-step

__global__ __launch_bounds__(256) void gemm_out(const signed char* __restrict__ sq,
                                                const signed char* __restrict__ wbT,
                                                const float* __restrict__ sscale,
                                                const float* __restrict__ wscale,
                                                const float* __restrict__ bias,
                                                float* __restrict__ out) {
  __shared__ __align__(16) signed char As[2][BM * BKB];   // 8 KB each
  __shared__ __align__(16) signed char Bs[2][BN * BKB];   // 16 KB each
  const int t = threadIdx.x;
  const int lane = t & 63;
  const int wave = t >> 6;
  const int wm = wave >> 1, wn = wave & 1;
  const int lr = lane & 15;
  const int slot = lane >> 4;     // 16B slot within 64B row
  const int m0 = blockIdx.y * BM;
  const int n0 = blockIdx.x * BN;

  i32x4 acc[4][8] = {};
  const int NT = 1024 / BKB;      // 16 K-steps

  auto STAGE = [&](int buf, int kt) {
    #pragma unroll
    for (int i = 0; i < 2; ++i) {          // A-tile: 512 16B-chunks
      int ch = i * 256 + t;
      int row = ch >> 2;
      int sl = ch & 3;
      int keb = (sl ^ ((row >> 1) & 3)) * 16;
      const signed char* ga = sq + (size_t)(m0 + row) * 1024 + kt * BKB + keb;
      __builtin_amdgcn_global_load_lds(
          (const __attribute__((address_space(1))) unsigned int*)ga,
          (__attribute__((address_space(3))) unsigned int*)(&As[buf][ch * 16]), 16, 0, 0);
    }
    #pragma unroll
    for (int i = 0; i < 4; ++i) {          // B-tile: 1024 16B-chunks
      int ch = i * 256 + t;
      int row = ch >> 2;
      int sl = ch & 3;
      int keb = (sl ^ ((row >> 1) & 3)) * 16;
      const signed char* gb = wbT + (size_t)(n0 + row) * 1024 + kt * BKB + keb;
      __builtin_amdgcn_global_load_lds(
          (const __attribute__((address_space(1))) unsigned int*)gb,
          (__attribute__((address_space(3))) unsigned int*)(&Bs[buf][ch * 16]), 16, 0, 0);
    }
  };

  STAGE(0, 0);
  __syncthreads();

  for (int kt = 0; kt < NT; ++kt) {
    const int cur = kt & 1;
    if (kt + 1 < NT) STAGE(cur ^ 1, kt + 1);   // prefetch overlaps compute

    i32x4 a[4], b[8];
    #pragma unroll
    for (int i = 0; i < 4; ++i) {
      int row = wm * 64 + i * 16 + lr;
      a[i] = *(const i32x4*)&As[cur][row * BKB + (slot ^ ((row >> 1) & 3)) * 16];
    }
    #pragma unroll
    for (int j = 0; j < 8; ++j) {
      int row = wn * 128 + j * 16 + lr;
      b[j] = *(const i32x4*)&Bs[cur][row * BKB + (slot ^ ((row >> 1) & 3)) * 16];
    }
    #pragma unroll
    for (int i = 0; i < 4; ++i)
      #pragma unroll
      for (int j = 0; j < 8; ++j)
        acc[i][j] = __builtin_amdgcn_mfma_i32_16x16x64_i8(a[i], b[j], acc[i][j], 0, 0, 0);
    __syncthreads();
  }

  float bj[8], ws_[8];
  #pragma unroll
  for (int j = 0; j < 8; ++j) {
    int col = n0 + wn * 128 + j * 16 + lr;
    bj[j] = bias[col];
    ws_[j] = wscale[col];
  }
  const int orow = slot * 4;
  float ss[4][4];
  #pragma unroll
  for (int i = 0; i < 4; ++i)
    #pragma unroll
    for (int r = 0; r < 4; ++r) {
      int row = m0 + wm * 64 + i * 16 + orow + r;
      ss[i][r] = (row < N_NODES) ? sscale[row] : 0.f;
    }

  #pragma unroll
  for (int i = 0; i < 4; ++i) {
    #pragma unroll
    for (int j = 0; j < 8; ++j) {
      #pragma unroll
      for (int r = 0; r < 4; ++r) {
        int row = m0 + wm * 64 + i * 16 + orow + r;
        if (row < N_NODES) {
          int col = n0 + wn * 128 + j * 16 + lr;
          float v = (float)acc[i][j][r] * ss[i][r] * ws_[j] + bj[j];
          __builtin_nontemporal_store(fmaxf(v, 0.f), out + (size_t)row * 512 + col);
        }
      }
    }
  }
}

// ---------------- launch ----------------
extern "C" void kernel_launch(void* const* d_in, const int* in_sizes, int n_in,
                              void* d_out, int out_size, void* d_ws, size_t ws_size,
                              hipStream_t stream) {
  const float* x     = (const float*)d_in[0];
  const float* w0    = (const float*)d_in[1];
  const float* w1    = (const float*)d_in[2];
  const float* bias  = (const float*)d_in[3];
  const float* vals0 = (const float*)d_in[4];
  const float* vals1 = (const float*)d_in[5];
  const int*   rows0 = (const int*)d_in[6];
  const int*   cols0 = (const int*)d_in[7];
  const int*   rows1 = (const int*)d_in[8];
  const int*   cols1 = (const int*)d_in[9];
  float* out = (float*)d_out;

  char* ws = (char*)d_ws;
  size_t off = 0;
  auto alloc = [&](size_t bytes) -> char* {
    char* p = ws + off;
    off += (bytes + 255) & ~(size_t)255;
    return p;
  };
  unsigned char*  xq     = (unsigned char*)alloc((size_t)N_NODES * D);      // 25.6 MB
  float*          scale  = (float*)alloc((size_t)N_NODES * sizeof(float));  // 0.2 MB
  signed char*    wbT    = (signed char*)alloc((size_t)512 * 1024);         // 0.5 MB
  float*          wscale = (float*)alloc(512 * sizeof(float));
  signed char*    sq     = (signed char*)alloc((size_t)MPAD * 1024);        // 51.2 MB
  float*          sscale = (float*)alloc((size_t)MPAD * sizeof(float));     // 0.2 MB
  int* cnt  = (int*)alloc(2 * N_NODES * sizeof(int));                       // 0.4 MB
  unsigned* e0 = (unsigned*)alloc((size_t)N_NODES * CAP * 4);               // 16 MB
  unsigned* e1 = (unsigned*)alloc((size_t)N_NODES * CAP * 4);               // 16 MB

  prep<<<12726, 256, 0, stream>>>(x, w0, w1, xq, scale, wbT, wscale, cnt);
  fill_bucket<<<1024, 256, 0, stream>>>(rows0, cols0, vals0, rows1, cols1, vals1,
                                        scale, cnt, cnt + N_NODES, e0, e1);
  spmm_sorted<<<N_NODES / 4, 256, 0, stream>>>(xq, cnt, e0, cnt + N_NODES, e1, sq, sscale);
  gemm_out<<<dim3(512 / BN, MPAD / BM), 256, 0, stream>>>(sq, wbT, sscale, wscale, bias, out);
}

// Round 18
// 499.482 us; speedup vs baseline: 1.0200x; 1.0200x over previous
//
#include <hip/hip_runtime.h>
#include <cstdint>
#include <cstddef>

#define N_NODES 50000
#define N_EDGES 1600000
#define D 512
#define MPAD 50048   // 391 * 128, padded M for GEMM tiles
#define NPX 6250     // nodes per XCD dest-range (50000/8)
#define CAP 80       // bucket capacity; Poisson(32) tail beyond 80 ~ 4e-12/row
#define TILE_SHIFT 11          // 2048-row source tiles (1 MB of xq each)
#define NTILES 25              // ceil(50000/2048)

typedef __attribute__((ext_vector_type(8))) short bf16x8;
typedef __attribute__((ext_vector_type(4))) float f32x4;
typedef __attribute__((ext_vector_type(8))) unsigned short u16x8;
typedef __attribute__((ext_vector_type(4))) int i32x4;

static __device__ __forceinline__ unsigned short f2bf(float f) {
  unsigned u = __float_as_uint(f);
  u += 0x7fffu + ((u >> 16) & 1u);   // RNE
  return (unsigned short)(u >> 16);
}

// ---------------- prep: x -> biased-u8 rows + scale, w transpose, zero cnt ----------------
// [0,12500): 1 wave = 1 row. rowmax via shfl_xor; u = rint(x*127/max)+128 in [1,255].
// Biased-unsigned storage lets spmm dequant with single-op v_cvt_f32_ubyte0..3.
// [12500,12628): 64x64 LDS transpose of w0/w1 -> wbT[j][k]=Wcat[k][j] (bf16).
// [12628,12726): zero cnt[100000].
__global__ __launch_bounds__(256) void prep(const float* __restrict__ x,
                                            const float* __restrict__ w0,
                                            const float* __restrict__ w1,
                                            unsigned char* __restrict__ xq,
                                            float* __restrict__ scale,
                                            unsigned short* __restrict__ wbT,
                                            int* __restrict__ cnt) {
  __shared__ float ts[64][68];
  const int t = threadIdx.x;
  if (blockIdx.x < 12500) {
    const int lane = t & 63;
    const int wave = t >> 6;
    const int n = blockIdx.x * 4 + wave;
    const float* xr = x + (size_t)n * D + lane * 8;
    f32x4 f0 = __builtin_nontemporal_load((const f32x4*)xr);
    f32x4 f1 = __builtin_nontemporal_load((const f32x4*)xr + 1);
    float m = fmaxf(fmaxf(fmaxf(fabsf(f0[0]), fabsf(f0[1])), fmaxf(fabsf(f0[2]), fabsf(f0[3]))),
                    fmaxf(fmaxf(fabsf(f1[0]), fabsf(f1[1])), fmaxf(fabsf(f1[2]), fabsf(f1[3]))));
    #pragma unroll
    for (int off = 32; off >= 1; off >>= 1) m = fmaxf(m, __shfl_xor(m, off, 64));
    m = fmaxf(m, 1e-20f);
    const float inv = 127.0f / m;
    int q[8];
    q[0] = (int)rintf(f0[0] * inv) + 128; q[1] = (int)rintf(f0[1] * inv) + 128;
    q[2] = (int)rintf(f0[2] * inv) + 128; q[3] = (int)rintf(f0[3] * inv) + 128;
    q[4] = (int)rintf(f1[0] * inv) + 128; q[5] = (int)rintf(f1[1] * inv) + 128;
    q[6] = (int)rintf(f1[2] * inv) + 128; q[7] = (int)rintf(f1[3] * inv) + 128;
    unsigned lo = (q[0] & 0xff) | ((q[1] & 0xff) << 8) | ((q[2] & 0xff) << 16) | ((unsigned)(q[3] & 0xff) << 24);
    unsigned hi = (q[4] & 0xff) | ((q[5] & 0xff) << 8) | ((q[6] & 0xff) << 16) | ((unsigned)(q[7] & 0xff) << 24);
    *(uint2*)(xq + (size_t)n * D + lane * 8) = make_uint2(lo, hi);
    if (lane == 0) scale[n] = m * (1.0f / 127.0f);
  } else if (blockIdx.x < 12628) {
    const int bid2 = blockIdx.x - 12500;    // 0..127
    const int m = bid2 >> 6;                // 0: w0, 1: w1
    const int tile = bid2 & 63;
    const int k0 = (tile >> 3) * 64;
    const int j0 = (tile & 7) * 64;
    const float* W = m ? w1 : w0;
    const int tr = t >> 4;
    const int tc = (t & 15) * 4;
    #pragma unroll
    for (int it = 0; it < 4; ++it) {
      int kk = tr + it * 16;
      float4 v = *(const float4*)&W[(size_t)(k0 + kk) * 512 + j0 + tc];
      ts[kk][tc] = v.x; ts[kk][tc + 1] = v.y; ts[kk][tc + 2] = v.z; ts[kk][tc + 3] = v.w;
    }
    __syncthreads();
    const int jl = t >> 3;
    const int kl = (t & 7) * 8;
    #pragma unroll
    for (int it = 0; it < 2; ++it) {
      int j = jl + it * 32;
      u16x8 o;
      #pragma unroll
      for (int q2 = 0; q2 < 8; ++q2) o[q2] = f2bf(ts[kl + q2][j]);
      *(u16x8*)&wbT[(size_t)(j0 + j) * 1024 + m * 512 + k0 + kl] = o;
    }
  } else {
    int q2 = (int)(blockIdx.x - 12628) * 256 + t;
    if (q2 < 25000) ((i32x4*)cnt)[q2] = (i32x4)0;
  }
}

// ---------------- bucket fill, XCD-local dest ranges ----------------
// Edge packed 4B: col(u16) | bf16(v * scale[col]) << 16 — scale folded here.
__global__ __launch_bounds__(256) void fill_bucket(
    const int* __restrict__ r0, const int* __restrict__ co0, const float* __restrict__ v0,
    const int* __restrict__ r1, const int* __restrict__ co1, const float* __restrict__ v1,
    const float* __restrict__ scale,
    int* __restrict__ cnt0, int* __restrict__ cnt1,
    unsigned* __restrict__ e0, unsigned* __restrict__ e1) {
  const int nq = N_EDGES / 4;
  const int lo = (int)(blockIdx.x & 7) * NPX;
  const int hi = lo + NPX;
  const int stride = (1024 >> 3) * 256;
  for (int i = (int)(blockIdx.x >> 3) * 256 + threadIdx.x; i < 2 * nq; i += stride) {
    if (i < nq) {
      i32x4 r = ((const i32x4*)r0)[i];
      i32x4 c = ((const i32x4*)co0)[i];
      f32x4 v = ((const f32x4*)v0)[i];
      #pragma unroll
      for (int k = 0; k < 4; ++k) {
        if (r[k] >= lo && r[k] < hi) {
          int slot = atomicAdd(&cnt0[r[k]], 1);
          if (slot < CAP)
            e0[(size_t)r[k] * CAP + slot] =
                (unsigned)c[k] | ((unsigned)f2bf(v[k] * scale[c[k]]) << 16);
        }
      }
    } else {
      int j = i - nq;
      i32x4 r = ((const i32x4*)r1)[j];
      i32x4 c = ((const i32x4*)co1)[j];
      f32x4 v = ((const f32x4*)v1)[j];
      #pragma unroll
      for (int k = 0; k < 4; ++k) {
        if (r[k] >= lo && r[k] < hi) {
          int slot = atomicAdd(&cnt1[r[k]], 1);
          if (slot < CAP)
            e1[(size_t)r[k] * CAP + slot] =
                (unsigned)c[k] | ((unsigned)f2bf(v[k] * scale[c[k]]) << 16);
        }
      }
    }
  }
}

// a[i] += v * u8_i  (biased); compiler lowers byte-extract+cvt to v_cvt_f32_ubyte0..3
static __device__ __forceinline__ void acc8u(float* a, uint2 q, float v) {
  a[0] += v * (float)(q.x & 0xffu);
  a[1] += v * (float)((q.x >> 8) & 0xffu);
  a[2] += v * (float)((q.x >> 16) & 0xffu);
  a[3] += v * (float)((q.x >> 24) & 0xffu);
  a[4] += v * (float)(q.y & 0xffu);
  a[5] += v * (float)((q.y >> 8) & 0xffu);
  a[6] += v * (float)((q.y >> 16) & 0xffu);
  a[7] += v * (float)((q.y >> 24) & 0xffu);
}

// ---------------- SpMM (biased-u8 gather) with per-bucket source-tile counting sort ----------------
// Structure identical to the proven round-12 kernel; dequant is cvt_ubyte + fma,
// un-bias a[i] -= 128*sum(v) at the end. Keep VGPR low -> ~79% occupancy.
__global__ __launch_bounds__(256) void spmm_sorted(const unsigned char* __restrict__ xq,
    const int* __restrict__ cnt0, const unsigned* __restrict__ e0,
    const int* __restrict__ cnt1, const unsigned* __restrict__ e1,
    unsigned short* __restrict__ s) {
  __shared__ unsigned sed[4][2][CAP];
  __shared__ int cur[4][2][NTILES];
  __shared__ unsigned short starts[4][2][NTILES + 1];
  const int t = threadIdx.x;
  const int lane = t & 63;
  const int wave = t >> 6;
  const int n = blockIdx.x * 4 + wave;   // 12500 blocks * 4 waves = 50000 rows
  const int c0 = lane * 8;               // 8 bytes per lane

  int deg0 = cnt0[n]; if (deg0 > CAP) deg0 = CAP;
  int deg1 = cnt1[n]; if (deg1 > CAP) deg1 = CAP;
  const unsigned* eb0 = e0 + (size_t)n * CAP;
  const unsigned* eb1 = e1 + (size_t)n * CAP;

  // zero histograms
  for (int b = lane; b < 2 * NTILES; b += 64) ((int*)cur[wave])[b] = 0;
  __syncthreads();

  // load edges (coalesced, stash in regs) + histogram by src-tile
  unsigned my0[2] = {0u, 0u}, my1[2] = {0u, 0u};
  #pragma unroll
  for (int q = 0; q < 2; ++q) {
    int p = lane + q * 64;
    if (p < deg0) {
      unsigned m = eb0[p]; my0[q] = m;
      atomicAdd(&cur[wave][0][(m & 0xffffu) >> TILE_SHIFT], 1);
    }
    if (p < deg1) {
      unsigned m = eb1[p]; my1[q] = m;
      atomicAdd(&cur[wave][1][(m & 0xffffu) >> TILE_SHIFT], 1);
    }
  }
  __syncthreads();

  // exclusive prefix (lane 0 -> sup0, lane 1 -> sup1); cur becomes the cursor
  if (lane < 2) {
    int acc2 = 0;
    for (int t2 = 0; t2 < NTILES; ++t2) {
      starts[wave][lane][t2] = (unsigned short)acc2;
      int h = cur[wave][lane][t2];
      cur[wave][lane][t2] = acc2;
      acc2 += h;
    }
    starts[wave][lane][NTILES] = (unsigned short)acc2;
  }
  __syncthreads();

  // scatter into sorted order
  #pragma unroll
  for (int q = 0; q < 2; ++q) {
    int p = lane + q * 64;
    if (p < deg0) {
      unsigned m = my0[q];
      int pos = atomicAdd(&cur[wave][0][(m & 0xffffu) >> TILE_SHIFT], 1);
      sed[wave][0][pos] = m;
    }
    if (p < deg1) {
      unsigned m = my1[q];
      int pos = atomicAdd(&cur[wave][1][(m & 0xffffu) >> TILE_SHIFT], 1);
      sed[wave][1][pos] = m;
    }
  }
  __syncthreads();

  // Phase B: tile-ordered gather-accumulate (ubyte dequant), track sum(v) per support
  float acc[2][8] = {};
  float sumv[2] = {0.f, 0.f};
  for (int t2 = 0; t2 < NTILES; ++t2) {
    #pragma unroll
    for (int sup = 0; sup < 2; ++sup) {
      float* a = acc[sup];
      float sv = 0.f;
      int p = starts[wave][sup][t2];
      const int pe = starts[wave][sup][t2 + 1];
      for (; p + 1 < pe; p += 2) {
        unsigned mA = sed[wave][sup][p];      // wave-uniform: LDS broadcast
        unsigned mB = sed[wave][sup][p + 1];
        uint2 qA = *(const uint2*)(xq + (size_t)(mA & 0xffffu) * D + c0);
        uint2 qB = *(const uint2*)(xq + (size_t)(mB & 0xffffu) * D + c0);
        float vA = __uint_as_float(mA & 0xffff0000u);
        float vB = __uint_as_float(mB & 0xffff0000u);
        acc8u(a, qA, vA);
        acc8u(a, qB, vB);
        sv += vA + vB;
      }
      if (p < pe) {
        unsigned m = sed[wave][sup][p];
        uint2 q = *(const uint2*)(xq + (size_t)(m & 0xffffu) * D + c0);
        float v = __uint_as_float(m & 0xffff0000u);
        acc8u(a, q, v);
        sv += v;
      }
      sumv[sup] += sv;
    }
  }

  u16x8 o0, o1;
  #pragma unroll
  for (int i = 0; i < 8; ++i) {
    o0[i] = f2bf(acc[0][i] - 128.0f * sumv[0]);
    o1[i] = f2bf(acc[1][i] - 128.0f * sumv[1]);
  }
  *(u16x8*)(s + (size_t)n * 1024 + c0) = o0;
  *(u16x8*)(s + (size_t)n * 1024 + 512 + c0) = o1;
}

// ---------------- GEMM: out = relu( s[MPAD][1024] @ Wcat[1024][512] + b ) ----------------
// BM=128, BN=256 (proven round-12/13/14 config). 4 waves; wave owns 64x128.
// XOR-swizzled LDS; 2-phase double buffer via global_load_lds prefetch.
#define BM 128
#define BN 256
#define BK 32

__global__ __launch_bounds__(256) void gemm_out(const unsigned short* __restrict__ s,
                                                const unsigned short* __restrict__ wbT,
                                                const float* __restrict__ bias,
                                                float* __restrict__ out) {
  __shared__ __align__(16) unsigned short As[2][BM * BK];
  __shared__ __align__(16) unsigned short Bs[2][BN * BK];
  const int t = threadIdx.x;
  const int lane = t & 63;
  const int wave = t >> 6;
  const int wm = wave >> 1, wn = wave & 1;
  const int lr = lane & 15;
  const int slot = lane >> 4;
  const int m0 = blockIdx.y * BM;
  const int n0 = blockIdx.x * BN;

  f32x4 acc[4][8] = {};
  const int NT = 1024 / BK;

  auto STAGE = [&](int buf, int kt) {
    #pragma unroll
    for (int i = 0; i < 2; ++i) {
      int ch = i * 256 + t;
      int row = ch >> 2;
      int sl = ch & 3;
      int ke = (sl ^ ((row >> 1) & 3)) * 8;
      const unsigned short* ga = s + (size_t)(m0 + row) * 1024 + kt * BK + ke;
      __builtin_amdgcn_global_load_lds(
          (const __attribute__((address_space(1))) unsigned int*)ga,
          (__attribute__((address_space(3))) unsigned int*)(&As[buf][ch * 8]), 16, 0, 0);
    }
    #pragma unroll
    for (int i = 0; i < 4; ++i) {
      int ch = i * 256 + t;
      int row = ch >> 2;
      int sl = ch & 3;
      int ke = (sl ^ ((row >> 1) & 3)) * 8;
      const unsigned short* gb = wbT + (size_t)(n0 + row) * 1024 + kt * BK + ke;
      __builtin_amdgcn_global_load_lds(
          (const __attribute__((address_space(1))) unsigned int*)gb,
          (__attribute__((address_space(3))) unsigned int*)(&Bs[buf][ch * 8]), 16, 0, 0);
    }
  };

  STAGE(0, 0);
  __syncthreads();

  for (int kt = 0; kt < NT; ++kt) {
    const int cur = kt & 1;
    if (kt + 1 < NT) STAGE(cur ^ 1, kt + 1);

    bf16x8 a[4], b[8];
    #pragma unroll
    for (int i = 0; i < 4; ++i) {
      int row = wm * 64 + i * 16 + lr;
      a[i] = *(const bf16x8*)&As[cur][row * BK + (slot ^ ((row >> 1) & 3)) * 8];
    }
    #pragma unroll
    for (int j = 0; j < 8; ++j) {
      int row = wn * 128 + j * 16 + lr;
      b[j] = *(const bf16x8*)&Bs[cur][row * BK + (slot ^ ((row >> 1) & 3)) * 8];
    }
    #pragma unroll
    for (int i = 0; i < 4; ++i)
      #pragma unroll
      for (int j = 0; j < 8; ++j)
        acc[i][j] = __builtin_amdgcn_mfma_f32_16x16x32_bf16(a[i], b[j], acc[i][j], 0, 0, 0);
    __syncthreads();
  }

  float bj[8];
  #pragma unroll
  for (int j = 0; j < 8; ++j) bj[j] = bias[n0 + wn * 128 + j * 16 + lr];

  const int orow = slot * 4;
  #pragma unroll
  for (int i = 0; i < 4; ++i) {
    #pragma unroll
    for (int j = 0; j < 8; ++j) {
      #pragma unroll
      for (int r = 0; r < 4; ++r) {
        int row = m0 + wm * 64 + i * 16 + orow + r;
        if (row < N_NODES) {
          int col = n0 + wn * 128 + j * 16 + lr;
          __builtin_nontemporal_store(fmaxf(acc[i][j][r] + bj[j], 0.f),
                                      out + (size_t)row * 512 + col);
        }
      }
    }
  }
}

// ---------------- launch ----------------
extern "C" void kernel_launch(void* const* d_in, const int* in_sizes, int n_in,
                              void* d_out, int out_size, void* d_ws, size_t ws_size,
                              hipStream_t stream) {
  const float* x     = (const float*)d_in[0];
  const float* w0    = (const float*)d_in[1];
  const float* w1    = (const float*)d_in[2];
  const float* bias  = (const float*)d_in[3];
  const float* vals0 = (const float*)d_in[4];
  const float* vals1 = (const float*)d_in[5];
  const int*   rows0 = (const int*)d_in[6];
  const int*   cols0 = (const int*)d_in[7];
  const int*   rows1 = (const int*)d_in[8];
  const int*   cols1 = (const int*)d_in[9];
  float* out = (float*)d_out;

  char* ws = (char*)d_ws;
  size_t off = 0;
  auto alloc = [&](size_t bytes) -> char* {
    char* p = ws + off;
    off += (bytes + 255) & ~(size_t)255;
    return p;
  };
  unsigned char*  xq    = (unsigned char*)alloc((size_t)N_NODES * D);      // 25.6 MB
  float*          scale = (float*)alloc((size_t)N_NODES * sizeof(float));  // 0.2 MB
  unsigned short* wbT   = (unsigned short*)alloc((size_t)512 * 1024 * 2);  // 1 MB
  unsigned short* s     = (unsigned short*)alloc((size_t)MPAD * 1024 * 2); // 102.5 MB
  int* cnt  = (int*)alloc(2 * N_NODES * sizeof(int));                      // 0.4 MB
  unsigned* e0 = (unsigned*)alloc((size_t)N_NODES * CAP * 4);              // 16 MB
  unsigned* e1 = (unsigned*)alloc((size_t)N_NODES * CAP * 4);              // 16 MB

  prep<<<12726, 256, 0, stream>>>(x, w0, w1, xq, scale, wbT, cnt);
  fill_bucket<<<1024, 256, 0, stream>>>(rows0, cols0, vals0, rows1, cols1, vals1,
                                        scale, cnt, cnt + N_NODES, e0, e1);
  spmm_sorted<<<N_NODES / 4, 256, 0, stream>>>(xq, cnt, e0, cnt + N_NODES, e1, s);
  gemm_out<<<dim3(512 / BN, MPAD / BM), 256, 0, stream>>>(s, wbT, bias, out);
}